// Round 11
// baseline (352.093 us; speedup 1.0000x reference)
//
#include <hip/hip_runtime.h>
#include <hip/hip_bf16.h>

typedef __bf16 bf16x8 __attribute__((ext_vector_type(8)));
typedef float f32x4 __attribute__((ext_vector_type(4)));
typedef unsigned int u32x4 __attribute__((ext_vector_type(4)));

#define WSZ 12
#define NTOK 144
#define RES 256
#define NHW 22
#define NWIN (4*NHW*NHW)
#define SCALE 0.17677669529663687f
#define XS 200    // x row stride (bf16): 400 B, 16B-aligned, 2-way banks
#define QS 40     // q/k/ao plane row stride (bf16): 80 B, 16B-aligned
#define VTS 152   // vT row stride (bf16): 304 B, 16B-aligned
#define STS 148   // stg row stride (f32): 592 B, 16B-aligned

#define WQ_ELEMS (576*192)
#define WP_ELEMS (192*192)
#define WS_NEED ((WQ_ELEMS + WP_ELEMS) * 2)

// LDS byte offsets
#define OFF_Q  57600                       // q planes: 2 x [144][40] bf16
#define OFF_K  (OFF_Q + 2*11520)           // k planes: 2 x [144][40] bf16  (80640)
#define OFF_VT (OFF_K + 2*11520)           // vT: [2][32][152] bf16         (103680)
#define OFF_AO (OFF_VT + 2*32*VTS*2)       // ao planes: 2 x [144][40] bf16 (123136)
#define SMEM_BYTES (OFF_AO + 2*NTOK*QS*2)  // 146176 B
// stg overlays [0 .. 192*STS*4 = 113664) — xw/q/k/vT region, disjoint from ao

static __device__ __forceinline__ unsigned f2u(float f) {
    return (unsigned)__builtin_bit_cast(unsigned short, __float2bfloat16(f));
}
static __device__ __forceinline__ unsigned pk2(float a, float b) {
    return f2u(a) | (f2u(b) << 16);
}
static __device__ __forceinline__ bf16x8 ld8(const void* p) {
    return *(const bf16x8*)p;
}
static __device__ __forceinline__ bf16x8 wfrag(const float* p) {
    const float4* p4 = (const float4*)p;
    float4 lo = p4[0], hi = p4[1];
    u32x4 u = { pk2(lo.x, lo.y), pk2(lo.z, lo.w), pk2(hi.x, hi.y), pk2(hi.z, hi.w) };
    return __builtin_bit_cast(bf16x8, u);
}

__global__ __launch_bounds__(256) void conv_w(const float* __restrict__ wq,
                                              const float* __restrict__ wp,
                                              __hip_bfloat16* __restrict__ dst) {
    int i = blockIdx.x * 256 + threadIdx.x;
    if (i < WQ_ELEMS) dst[i] = __float2bfloat16(wq[i]);
    if (i < WP_ELEMS) dst[WQ_ELEMS + i] = __float2bfloat16(wp[i]);
}

template<bool WB>
__global__ __launch_bounds__(768, 3) void wsa_kernel(
    const float* __restrict__ x,
    const float* __restrict__ w_qkv,
    const float* __restrict__ w_proj,
    const __hip_bfloat16* __restrict__ wqb,
    const __hip_bfloat16* __restrict__ wpb,
    float* __restrict__ out)
{
    __shared__ __align__(16) unsigned char smem[SMEM_BYTES];
    __hip_bfloat16 (* const xw)[XS]  = reinterpret_cast<__hip_bfloat16(*)[XS]>(smem);
    float          (* const stg)[STS] = reinterpret_cast<float(*)[STS]>(smem);
    __hip_bfloat16* const vTp = reinterpret_cast<__hip_bfloat16*>(smem + OFF_VT);

    const int tid  = threadIdx.x;
    const int lane = tid & 63;
    const int wv   = tid >> 6;      // 0..11
    const int col  = lane & 15;
    const int grp  = lane >> 4;     // 0..3

    // XCD-aware swizzle (1936 % 8 == 0 -> bijective)
    const int wid0 = blockIdx.x;
    const int wid  = (wid0 & 7) * (NWIN / 8) + (wid0 >> 3);
    const int b    = wid / (NHW * NHW);
    const int r0   = wid % (NHW * NHW);
    const int wh   = r0 / NHW;
    const int ww   = r0 % NHW;

    // ---- stage x window (reflect pad) into LDS bf16 [t][c] ----
    for (int u = tid; u < 24 * NTOK; u += 768) {   // u = c8*144 + t
        int c8 = u / NTOK;
        int t  = u - c8 * NTOK;
        int ty = t / WSZ, tx = t - ty * WSZ;
        int h = wh * WSZ + ty; if (h >= RES) h = 2 * RES - 2 - h;
        int w = ww * WSZ + tx; if (w >= RES) w = 2 * RES - 2 - w;
        const float* px = x + ((size_t)(b * 192 + c8 * 8) * RES + h) * RES + w;
        u32x4 uv;
        #pragma unroll
        for (int j = 0; j < 4; ++j)
            uv[j] = pk2(px[(size_t)(2 * j) * RES * RES], px[(size_t)(2 * j + 1) * RES * RES]);
        *(u32x4*)&xw[t][c8 * 8] = uv;
    }
    __syncthreads();

    f32x4 pacc[9];   // proj accumulators; wave owns oc-tile wv
    #pragma unroll
    for (int m = 0; m < 9; ++m) pacc[m] = (f32x4){0.f, 0.f, 0.f, 0.f};

    // qkv wave role: (mh, n6); n6 -> (kind, h2q); wave covers both dh halves
    const int mh   = wv & 1;
    const int n6   = wv >> 1;       // 0..5
    const int kind = n6 >> 1;       // 0=q 1=k 2=v
    const int h2q  = n6 & 1;
    const int mt0  = mh ? 4 : 0;
    const int nmt  = mh ? 5 : 4;    // mh=1 also owns mt8

    auto do_proj = [&](int hpp) {
        #pragma unroll
        for (int h2 = 0; h2 < 2; ++h2) {
            const int hh = hpp * 2 + h2;
            const bf16x8 Bf = WB ? ld8(wpb + (size_t)(wv * 16 + col) * 192 + hh * 32 + grp * 8)
                                 : wfrag(w_proj + (size_t)(wv * 16 + col) * 192 + hh * 32 + grp * 8);
            const __hip_bfloat16 (* const aoPl)[QS] =
                reinterpret_cast<const __hip_bfloat16(*)[QS]>(smem + OFF_AO + h2 * 11520);
            #pragma unroll
            for (int mt = 0; mt < 9; ++mt) {
                const bf16x8 Af = ld8(&aoPl[mt * 16 + col][grp * 8]);
                pacc[mt] = __builtin_amdgcn_mfma_f32_16x16x32_bf16(Af, Bf, pacc[mt], 0, 0, 0);
            }
        }
    };

    for (int hp = 0; hp < 3; ++hp) {
        // ---- merged phase: qkv(hp) + proj(hp-1) ----
        {
            const int hh    = hp * 2 + h2q;
            const int rbase = kind * 192 + hh * 32;

            // HOIST: issue all 12 qkv B-fragment loads before the MFMA loop
            bf16x8 Bq[6][2];
            #pragma unroll
            for (int k0 = 0; k0 < 6; ++k0) {
                Bq[k0][0] = WB ? ld8(wqb + (size_t)(rbase + col) * 192 + k0 * 32 + grp * 8)
                               : wfrag(w_qkv + (size_t)(rbase + col) * 192 + k0 * 32 + grp * 8);
                Bq[k0][1] = WB ? ld8(wqb + (size_t)(rbase + 16 + col) * 192 + k0 * 32 + grp * 8)
                               : wfrag(w_qkv + (size_t)(rbase + 16 + col) * 192 + k0 * 32 + grp * 8);
            }

            f32x4 acc[2][5];
            #pragma unroll
            for (int d = 0; d < 2; ++d)
                #pragma unroll
                for (int m = 0; m < 5; ++m) acc[d][m] = (f32x4){0.f, 0.f, 0.f, 0.f};
            #pragma unroll
            for (int k0 = 0; k0 < 6; ++k0) {
                #pragma unroll
                for (int m = 0; m < 5; ++m) {
                    if (m < nmt) {
                        const bf16x8 Af = ld8(&xw[(mt0 + m) * 16 + col][k0 * 32 + grp * 8]);
                        acc[0][m] = __builtin_amdgcn_mfma_f32_16x16x32_bf16(Af, Bq[k0][0], acc[0][m], 0, 0, 0);
                        acc[1][m] = __builtin_amdgcn_mfma_f32_16x16x32_bf16(Af, Bq[k0][1], acc[1][m], 0, 0, 0);
                    }
                }
            }
            const float qs = (kind == 0) ? SCALE : 1.f;
            if (kind < 2) {
                __hip_bfloat16 (* const pl)[QS] = reinterpret_cast<__hip_bfloat16(*)[QS]>(
                    smem + (kind == 0 ? OFF_Q : OFF_K) + h2q * 11520);
                #pragma unroll
                for (int m = 0; m < 5; ++m) if (m < nmt) {
                    #pragma unroll
                    for (int r = 0; r < 4; ++r) {
                        const int trow = (mt0 + m) * 16 + grp * 4 + r;
                        pl[trow][col]      = __float2bfloat16(acc[0][m][r] * qs);
                        pl[trow][16 + col] = __float2bfloat16(acc[1][m][r] * qs);
                    }
                }
            } else {
                #pragma unroll
                for (int m = 0; m < 5; ++m) if (m < nmt) {
                    #pragma unroll
                    for (int r = 0; r < 4; ++r) {
                        const int t  = (mt0 + m) * 16 + grp * 4 + r;
                        const int ti = t / WSZ, tj = t - ti * WSZ;
                        const int cs   = (ti % 3) * 3 + (tj % 3);
                        const int ctok = (ti / 3) * 4 + (tj / 3);
                        vTp[(size_t)(h2q * 32 + col) * VTS + cs * 16 + ctok]      = __float2bfloat16(acc[0][m][r]);
                        vTp[(size_t)(h2q * 32 + 16 + col) * VTS + cs * 16 + ctok] = __float2bfloat16(acc[1][m][r]);
                    }
                }
            }
            if (hp > 0) do_proj(hp - 1);
        }
        __syncthreads();

        // ---- coset attention: 18 tasks (h2, coset) over 12 waves; writes ao ----
        for (int u = wv; u < 18; u += 12) {
            const int h2 = u / 9;
            const int cs = u % 9;
            __hip_bfloat16 (* const qPl)[QS] = reinterpret_cast<__hip_bfloat16(*)[QS]>(smem + OFF_Q + h2 * 11520);
            __hip_bfloat16 (* const kPl)[QS] = reinterpret_cast<__hip_bfloat16(*)[QS]>(smem + OFF_K + h2 * 11520);
            __hip_bfloat16 (* const aoPl)[QS] = reinterpret_cast<__hip_bfloat16(*)[QS]>(smem + OFF_AO + h2 * 11520);
            const int ci = cs / 3, cj = cs % 3;
            const int tcol = (ci + 3 * (col >> 2)) * WSZ + cj + 3 * (col & 3);
            const bf16x8 Kf = ld8(&kPl[tcol][grp * 8]);
            const bf16x8 Qf = ld8(&qPl[tcol][grp * 8]);
            f32x4 S = {0.f, 0.f, 0.f, 0.f};
            S = __builtin_amdgcn_mfma_f32_16x16x32_bf16(Kf, Qf, S, 0, 0, 0);
            // lane holds S^T: key m = grp*4+r, query n = col
            float e[4]; float mx = -1e30f;
            #pragma unroll
            for (int r = 0; r < 4; ++r) {
                float s = (grp * 4 + r == col) ? -1e30f : S[r];
                e[r] = s;
                mx = fmaxf(mx, s);
            }
            mx = fmaxf(mx, __shfl_xor(mx, 16));
            mx = fmaxf(mx, __shfl_xor(mx, 32));
            float sum = 0.f;
            #pragma unroll
            for (int r = 0; r < 4; ++r) { e[r] = __expf(e[r] - mx); sum += e[r]; }
            sum += __shfl_xor(sum, 16);
            sum += __shfl_xor(sum, 32);
            const float inv = 1.f / sum;
            const unsigned w0 = pk2(e[0] * inv, e[1] * inv);
            const unsigned w1 = pk2(e[2] * inv, e[3] * inv);
            // P -> B-fragment: lane(col,grp<2) holds P[q=col][k=grp*8+j]
            u32x4 pa = {0u, 0u, 0u, 0u};
            {
                const int sA = (col + 32 * grp) * 4;
                int q0 = __builtin_amdgcn_ds_bpermute(sA,      (int)w0);
                int q1 = __builtin_amdgcn_ds_bpermute(sA,      (int)w1);
                int q2 = __builtin_amdgcn_ds_bpermute(sA + 64, (int)w0);
                int q3 = __builtin_amdgcn_ds_bpermute(sA + 64, (int)w1);
                if (grp < 2) pa = (u32x4){(unsigned)q0, (unsigned)q1, (unsigned)q2, (unsigned)q3};
            }
            const bf16x8 PB = __builtin_bit_cast(bf16x8, pa);
            // swapped PV: O^T = mfma(A=V^T, B=P); lane holds 4 consecutive d -> b64 store
            #pragma unroll
            for (int d0 = 0; d0 < 2; ++d0) {
                const bf16x8 VA = ld8(&vTp[(size_t)(h2 * 32 + d0 * 16 + col) * VTS + cs * 16 + (grp & 1) * 8]);
                f32x4 O = {0.f, 0.f, 0.f, 0.f};
                O = __builtin_amdgcn_mfma_f32_16x16x32_bf16(VA, PB, O, 0, 0, 0);
                uint2 ov;
                ov.x = pk2(O[0], O[1]);
                ov.y = pk2(O[2], O[3]);
                *(uint2*)&aoPl[tcol][d0 * 16 + grp * 4] = ov;
            }
        }
        __syncthreads();
    }

    // ---- final proj for last head pair (reads ao only; stg region disjoint) ----
    do_proj(2);

    // ---- epilogue: stage all 192 oc as f32 [oc][t] (overlays dead x/q/k/vT) ----
    {
        const int ocl = wv * 16 + col;
        #pragma unroll
        for (int mt = 0; mt < 9; ++mt) {
            float4 v4 = make_float4(pacc[mt][0], pacc[mt][1], pacc[mt][2], pacc[mt][3]);
            *(float4*)&stg[ocl][mt * 16 + grp * 4] = v4;
        }
    }
    __syncthreads();
    #pragma unroll
    for (int it = 0; it < 9; ++it) {
        int v = tid + it * 768;          // 0..6911 = (oc, ty, seg)
        int seg = v % 3;
        int rest = v / 3;
        int ty = rest % 12;
        int oc = rest / 12;
        int h  = wh * WSZ + ty;
        int w0 = ww * WSZ + seg * 4;
        if (h < RES && w0 < RES) {
            float4 val = *(const float4*)&stg[oc][ty * 12 + seg * 4];
            *(float4*)&out[((size_t)(b * 192 + oc) * RES + h) * RES + w0] = val;
        }
    }
}

extern "C" void kernel_launch(void* const* d_in, const int* in_sizes, int n_in,
                              void* d_out, int out_size, void* d_ws, size_t ws_size,
                              hipStream_t stream) {
    const float* x      = (const float*)d_in[0];
    const float* w_qkv  = (const float*)d_in[1];
    const float* w_proj = (const float*)d_in[2];
    float* out = (float*)d_out;
    if (ws_size >= (size_t)WS_NEED) {
        __hip_bfloat16* wqb = (__hip_bfloat16*)d_ws;
        __hip_bfloat16* wpb = wqb + WQ_ELEMS;
        conv_w<<<dim3((WQ_ELEMS + 255) / 256), dim3(256), 0, stream>>>(w_qkv, w_proj, wqb);
        wsa_kernel<true><<<dim3(NWIN), dim3(768), 0, stream>>>(x, w_qkv, w_proj, wqb, wpb, out);
    } else {
        wsa_kernel<false><<<dim3(NWIN), dim3(768), 0, stream>>>(x, w_qkv, w_proj, nullptr, nullptr, out);
    }
}

// Round 12
// 331.587 us; speedup vs baseline: 1.0618x; 1.0618x over previous
//
#include <hip/hip_runtime.h>
#include <hip/hip_bf16.h>

typedef __bf16 bf16x8 __attribute__((ext_vector_type(8)));
typedef float f32x4 __attribute__((ext_vector_type(4)));
typedef unsigned int u32x4 __attribute__((ext_vector_type(4)));

#define WSZ 12
#define NTOK 144
#define RES 256
#define NHW 22
#define NWIN (4*NHW*NHW)
#define SCALE 0.17677669529663687f
#define XS 200    // x row stride (bf16): 400 B, 16B-aligned, 2-way banks
#define QS 40     // q/k/ao plane row stride (bf16): 80 B, 16B-aligned
#define VTS 152   // vT row stride (bf16): 304 B, 16B-aligned
#define STS 148   // stg row stride (f32): 592 B, 16B-aligned

#define WQ_ELEMS (576*192)
#define WP_ELEMS (192*192)
#define WS_NEED ((WQ_ELEMS + WP_ELEMS) * 2)

// LDS byte offsets
#define OFF_Q  57600                       // q planes: 2 x [144][40] bf16
#define OFF_K  (OFF_Q + 2*11520)           // k planes: 2 x [144][40] bf16  (80640)
#define OFF_VT (OFF_K + 2*11520)           // vT: [2][32][152] bf16         (103680)
#define OFF_AO (OFF_VT + 2*32*VTS*2)       // ao planes: 2 x [144][40] bf16 (123136)
#define SMEM_BYTES (OFF_AO + 2*NTOK*QS*2)  // 146176 B
// stg overlays [0 .. 192*STS*4 = 113664) — xw/q/k/vT region, disjoint from ao

static __device__ __forceinline__ unsigned f2u(float f) {
    return (unsigned)__builtin_bit_cast(unsigned short, __float2bfloat16(f));
}
static __device__ __forceinline__ unsigned pk2(float a, float b) {
    return f2u(a) | (f2u(b) << 16);
}
static __device__ __forceinline__ bf16x8 ld8(const void* p) {
    return *(const bf16x8*)p;
}
static __device__ __forceinline__ bf16x8 wfrag(const float* p) {
    const float4* p4 = (const float4*)p;
    float4 lo = p4[0], hi = p4[1];
    u32x4 u = { pk2(lo.x, lo.y), pk2(lo.z, lo.w), pk2(hi.x, hi.y), pk2(hi.z, hi.w) };
    return __builtin_bit_cast(bf16x8, u);
}

__global__ __launch_bounds__(256) void conv_w(const float* __restrict__ wq,
                                              const float* __restrict__ wp,
                                              __hip_bfloat16* __restrict__ dst) {
    int i = blockIdx.x * 256 + threadIdx.x;
    if (i < WQ_ELEMS) dst[i] = __float2bfloat16(wq[i]);
    if (i < WP_ELEMS) dst[WQ_ELEMS + i] = __float2bfloat16(wp[i]);
}

template<bool WB>
__global__ __launch_bounds__(768, 3) void wsa_kernel(
    const float* __restrict__ x,
    const float* __restrict__ w_qkv,
    const float* __restrict__ w_proj,
    const __hip_bfloat16* __restrict__ wqb,
    const __hip_bfloat16* __restrict__ wpb,
    float* __restrict__ out)
{
    __shared__ __align__(16) unsigned char smem[SMEM_BYTES];
    __hip_bfloat16 (* const xw)[XS]  = reinterpret_cast<__hip_bfloat16(*)[XS]>(smem);
    float          (* const stg)[STS] = reinterpret_cast<float(*)[STS]>(smem);
    __hip_bfloat16* const vTp = reinterpret_cast<__hip_bfloat16*>(smem + OFF_VT);

    const int tid  = threadIdx.x;
    const int lane = tid & 63;
    const int wv   = tid >> 6;      // 0..11
    const int col  = lane & 15;
    const int grp  = lane >> 4;     // 0..3

    // no XCD swizzle: FETCH (118 MB) is L3-resident; default consecutive-window
    // order has better natural L2 row locality (isolating R5's bundled swizzle)
    const int wid  = blockIdx.x;
    const int b    = wid / (NHW * NHW);
    const int r0   = wid % (NHW * NHW);
    const int wh   = r0 / NHW;
    const int ww   = r0 % NHW;

    // ---- stage x window (reflect pad) into LDS bf16 [t][c] ----
    for (int u = tid; u < 24 * NTOK; u += 768) {   // u = c8*144 + t
        int c8 = u / NTOK;
        int t  = u - c8 * NTOK;
        int ty = t / WSZ, tx = t - ty * WSZ;
        int h = wh * WSZ + ty; if (h >= RES) h = 2 * RES - 2 - h;
        int w = ww * WSZ + tx; if (w >= RES) w = 2 * RES - 2 - w;
        const float* px = x + ((size_t)(b * 192 + c8 * 8) * RES + h) * RES + w;
        u32x4 uv;
        #pragma unroll
        for (int j = 0; j < 4; ++j)
            uv[j] = pk2(px[(size_t)(2 * j) * RES * RES], px[(size_t)(2 * j + 1) * RES * RES]);
        *(u32x4*)&xw[t][c8 * 8] = uv;
    }
    __syncthreads();

    f32x4 pacc[9];   // proj accumulators; wave owns oc-tile wv
    #pragma unroll
    for (int m = 0; m < 9; ++m) pacc[m] = (f32x4){0.f, 0.f, 0.f, 0.f};

    // qkv wave role: (mh, n6); n6 -> (kind, h2q); wave covers both dh halves
    const int mh   = wv & 1;
    const int n6   = wv >> 1;       // 0..5
    const int kind = n6 >> 1;       // 0=q 1=k 2=v
    const int h2q  = n6 & 1;
    const int mt0  = mh ? 4 : 0;
    const int nmt  = mh ? 5 : 4;    // mh=1 also owns mt8

    auto do_proj = [&](int hpp) {
        #pragma unroll
        for (int h2 = 0; h2 < 2; ++h2) {
            const int hh = hpp * 2 + h2;
            const bf16x8 Bf = WB ? ld8(wpb + (size_t)(wv * 16 + col) * 192 + hh * 32 + grp * 8)
                                 : wfrag(w_proj + (size_t)(wv * 16 + col) * 192 + hh * 32 + grp * 8);
            const __hip_bfloat16 (* const aoPl)[QS] =
                reinterpret_cast<const __hip_bfloat16(*)[QS]>(smem + OFF_AO + h2 * 11520);
            #pragma unroll
            for (int mt = 0; mt < 9; ++mt) {
                const bf16x8 Af = ld8(&aoPl[mt * 16 + col][grp * 8]);
                pacc[mt] = __builtin_amdgcn_mfma_f32_16x16x32_bf16(Af, Bf, pacc[mt], 0, 0, 0);
            }
        }
    };

    for (int hp = 0; hp < 3; ++hp) {
        // ---- merged phase: qkv(hp) + proj(hp-1) ----
        {
            const int hh    = hp * 2 + h2q;
            const int rbase = kind * 192 + hh * 32;
            f32x4 acc[2][5];
            #pragma unroll
            for (int d = 0; d < 2; ++d)
                #pragma unroll
                for (int m = 0; m < 5; ++m) acc[d][m] = (f32x4){0.f, 0.f, 0.f, 0.f};
            #pragma unroll
            for (int k0 = 0; k0 < 6; ++k0) {
                const bf16x8 B0 = WB ? ld8(wqb + (size_t)(rbase + col) * 192 + k0 * 32 + grp * 8)
                                     : wfrag(w_qkv + (size_t)(rbase + col) * 192 + k0 * 32 + grp * 8);
                const bf16x8 B1 = WB ? ld8(wqb + (size_t)(rbase + 16 + col) * 192 + k0 * 32 + grp * 8)
                                     : wfrag(w_qkv + (size_t)(rbase + 16 + col) * 192 + k0 * 32 + grp * 8);
                #pragma unroll
                for (int m = 0; m < 5; ++m) {
                    if (m < nmt) {
                        const bf16x8 Af = ld8(&xw[(mt0 + m) * 16 + col][k0 * 32 + grp * 8]);
                        acc[0][m] = __builtin_amdgcn_mfma_f32_16x16x32_bf16(Af, B0, acc[0][m], 0, 0, 0);
                        acc[1][m] = __builtin_amdgcn_mfma_f32_16x16x32_bf16(Af, B1, acc[1][m], 0, 0, 0);
                    }
                }
            }
            const float qs = (kind == 0) ? SCALE : 1.f;
            if (kind < 2) {
                __hip_bfloat16 (* const pl)[QS] = reinterpret_cast<__hip_bfloat16(*)[QS]>(
                    smem + (kind == 0 ? OFF_Q : OFF_K) + h2q * 11520);
                #pragma unroll
                for (int m = 0; m < 5; ++m) if (m < nmt) {
                    #pragma unroll
                    for (int r = 0; r < 4; ++r) {
                        const int trow = (mt0 + m) * 16 + grp * 4 + r;
                        pl[trow][col]      = __float2bfloat16(acc[0][m][r] * qs);
                        pl[trow][16 + col] = __float2bfloat16(acc[1][m][r] * qs);
                    }
                }
            } else {
                #pragma unroll
                for (int m = 0; m < 5; ++m) if (m < nmt) {
                    #pragma unroll
                    for (int r = 0; r < 4; ++r) {
                        const int t  = (mt0 + m) * 16 + grp * 4 + r;
                        const int ti = t / WSZ, tj = t - ti * WSZ;
                        const int cs   = (ti % 3) * 3 + (tj % 3);
                        const int ctok = (ti / 3) * 4 + (tj / 3);
                        vTp[(size_t)(h2q * 32 + col) * VTS + cs * 16 + ctok]      = __float2bfloat16(acc[0][m][r]);
                        vTp[(size_t)(h2q * 32 + 16 + col) * VTS + cs * 16 + ctok] = __float2bfloat16(acc[1][m][r]);
                    }
                }
            }
            if (hp > 0) do_proj(hp - 1);
        }
        __syncthreads();

        // ---- coset attention: 18 tasks (h2, coset) over 12 waves; writes ao ----
        for (int u = wv; u < 18; u += 12) {
            const int h2 = u / 9;
            const int cs = u % 9;
            __hip_bfloat16 (* const qPl)[QS] = reinterpret_cast<__hip_bfloat16(*)[QS]>(smem + OFF_Q + h2 * 11520);
            __hip_bfloat16 (* const kPl)[QS] = reinterpret_cast<__hip_bfloat16(*)[QS]>(smem + OFF_K + h2 * 11520);
            __hip_bfloat16 (* const aoPl)[QS] = reinterpret_cast<__hip_bfloat16(*)[QS]>(smem + OFF_AO + h2 * 11520);
            const int ci = cs / 3, cj = cs % 3;
            const int tcol = (ci + 3 * (col >> 2)) * WSZ + cj + 3 * (col & 3);
            const bf16x8 Kf = ld8(&kPl[tcol][grp * 8]);
            const bf16x8 Qf = ld8(&qPl[tcol][grp * 8]);
            f32x4 S = {0.f, 0.f, 0.f, 0.f};
            S = __builtin_amdgcn_mfma_f32_16x16x32_bf16(Kf, Qf, S, 0, 0, 0);
            // lane holds S^T: key m = grp*4+r, query n = col
            float e[4]; float mx = -1e30f;
            #pragma unroll
            for (int r = 0; r < 4; ++r) {
                float s = (grp * 4 + r == col) ? -1e30f : S[r];
                e[r] = s;
                mx = fmaxf(mx, s);
            }
            mx = fmaxf(mx, __shfl_xor(mx, 16));
            mx = fmaxf(mx, __shfl_xor(mx, 32));
            float sum = 0.f;
            #pragma unroll
            for (int r = 0; r < 4; ++r) { e[r] = __expf(e[r] - mx); sum += e[r]; }
            sum += __shfl_xor(sum, 16);
            sum += __shfl_xor(sum, 32);
            const float inv = 1.f / sum;
            const unsigned w0 = pk2(e[0] * inv, e[1] * inv);
            const unsigned w1 = pk2(e[2] * inv, e[3] * inv);
            // P -> B-fragment: lane(col,grp<2) holds P[q=col][k=grp*8+j]
            u32x4 pa = {0u, 0u, 0u, 0u};
            {
                const int sA = (col + 32 * grp) * 4;
                int q0 = __builtin_amdgcn_ds_bpermute(sA,      (int)w0);
                int q1 = __builtin_amdgcn_ds_bpermute(sA,      (int)w1);
                int q2 = __builtin_amdgcn_ds_bpermute(sA + 64, (int)w0);
                int q3 = __builtin_amdgcn_ds_bpermute(sA + 64, (int)w1);
                if (grp < 2) pa = (u32x4){(unsigned)q0, (unsigned)q1, (unsigned)q2, (unsigned)q3};
            }
            const bf16x8 PB = __builtin_bit_cast(bf16x8, pa);
            // swapped PV: O^T = mfma(A=V^T, B=P)
            #pragma unroll
            for (int d0 = 0; d0 < 2; ++d0) {
                const bf16x8 VA = ld8(&vTp[(size_t)(h2 * 32 + d0 * 16 + col) * VTS + cs * 16 + (grp & 1) * 8]);
                f32x4 O = {0.f, 0.f, 0.f, 0.f};
                O = __builtin_amdgcn_mfma_f32_16x16x32_bf16(VA, PB, O, 0, 0, 0);
                #pragma unroll
                for (int r = 0; r < 4; ++r)
                    aoPl[tcol][d0 * 16 + grp * 4 + r] = __float2bfloat16(O[r]);
            }
        }
        __syncthreads();
    }

    // ---- final proj for last head pair (reads ao only; stg region disjoint) ----
    do_proj(2);

    // ---- epilogue: stage all 192 oc as f32 [oc][t] (overlays dead x/q/k/vT) ----
    {
        const int ocl = wv * 16 + col;
        #pragma unroll
        for (int mt = 0; mt < 9; ++mt) {
            float4 v4 = make_float4(pacc[mt][0], pacc[mt][1], pacc[mt][2], pacc[mt][3]);
            *(float4*)&stg[ocl][mt * 16 + grp * 4] = v4;
        }
    }
    __syncthreads();
    #pragma unroll
    for (int it = 0; it < 9; ++it) {
        int v = tid + it * 768;          // 0..6911 = (oc, ty, seg)
        int seg = v % 3;
        int rest = v / 3;
        int ty = rest % 12;
        int oc = rest / 12;
        int h  = wh * WSZ + ty;
        int w0 = ww * WSZ + seg * 4;
        if (h < RES && w0 < RES) {
            float4 val = *(const float4*)&stg[oc][ty * 12 + seg * 4];
            *(float4*)&out[((size_t)(b * 192 + oc) * RES + h) * RES + w0] = val;
        }
    }
}

extern "C" void kernel_launch(void* const* d_in, const int* in_sizes, int n_in,
                              void* d_out, int out_size, void* d_ws, size_t ws_size,
                              hipStream_t stream) {
    const float* x      = (const float*)d_in[0];
    const float* w_qkv  = (const float*)d_in[1];
    const float* w_proj = (const float*)d_in[2];
    float* out = (float*)d_out;
    if (ws_size >= (size_t)WS_NEED) {
        __hip_bfloat16* wqb = (__hip_bfloat16*)d_ws;
        __hip_bfloat16* wpb = wqb + WQ_ELEMS;
        conv_w<<<dim3((WQ_ELEMS + 255) / 256), dim3(256), 0, stream>>>(w_qkv, w_proj, wqb);
        wsa_kernel<true><<<dim3(NWIN), dim3(768), 0, stream>>>(x, w_qkv, w_proj, wqb, wpb, out);
    } else {
        wsa_kernel<false><<<dim3(NWIN), dim3(768), 0, stream>>>(x, w_qkv, w_proj, nullptr, nullptr, out);
    }
}

// Round 13
// 293.959 us; speedup vs baseline: 1.1978x; 1.1280x over previous
//
#include <hip/hip_runtime.h>
#include <hip/hip_bf16.h>

typedef __bf16 bf16x8 __attribute__((ext_vector_type(8)));
typedef float f32x4 __attribute__((ext_vector_type(4)));
typedef unsigned int u32x4 __attribute__((ext_vector_type(4)));

#define WSZ 12
#define NTOK 144
#define RES 256
#define NHW 22
#define NWIN (4*NHW*NHW)
#define SCALE 0.17677669529663687f
#define XS 200    // x row stride (bf16): 400 B, 16B-aligned, 2-way banks
#define QS 40     // q/k/ao plane row stride (bf16): 80 B, 16B-aligned
#define VTS 152   // vT row stride (bf16): 304 B, 16B-aligned
#define STS 148   // stg row stride (f32): 592 B, 16B-aligned

#define WQ_ELEMS (576*192)
#define WP_ELEMS (192*192)
#define WS_NEED ((WQ_ELEMS + WP_ELEMS) * 2)

// LDS byte offsets
#define OFF_Q  57600                       // q planes: 2 x [144][40] bf16
#define OFF_K  (OFF_Q + 2*11520)           // k planes: 2 x [144][40] bf16  (80640)
#define OFF_VT (OFF_K + 2*11520)           // vT: [2][32][152] bf16         (103680)
#define OFF_AO (OFF_VT + 2*32*VTS*2)       // ao planes: 2 x [144][40] bf16 (123136)
#define SMEM_BYTES (OFF_AO + 2*NTOK*QS*2)  // 146176 B
// stg overlays [0 .. 192*STS*4 = 113664) — xw/q/k/vT region, disjoint from ao

static __device__ __forceinline__ unsigned f2u(float f) {
    return (unsigned)__builtin_bit_cast(unsigned short, __float2bfloat16(f));
}
static __device__ __forceinline__ unsigned pk2(float a, float b) {
    return f2u(a) | (f2u(b) << 16);
}
static __device__ __forceinline__ bf16x8 ld8(const void* p) {
    return *(const bf16x8*)p;
}
static __device__ __forceinline__ bf16x8 wfrag(const float* p) {
    const float4* p4 = (const float4*)p;
    float4 lo = p4[0], hi = p4[1];
    u32x4 u = { pk2(lo.x, lo.y), pk2(lo.z, lo.w), pk2(hi.x, hi.y), pk2(hi.z, hi.w) };
    return __builtin_bit_cast(bf16x8, u);
}

__global__ __launch_bounds__(256) void conv_w(const float* __restrict__ wq,
                                              const float* __restrict__ wp,
                                              __hip_bfloat16* __restrict__ dst) {
    int i = blockIdx.x * 256 + threadIdx.x;
    if (i < WQ_ELEMS) dst[i] = __float2bfloat16(wq[i]);
    if (i < WP_ELEMS) dst[WQ_ELEMS + i] = __float2bfloat16(wp[i]);
}

template<bool WB>
__global__ __launch_bounds__(768, 3) void wsa_kernel(
    const float* __restrict__ x,
    const float* __restrict__ w_qkv,
    const float* __restrict__ w_proj,
    const __hip_bfloat16* __restrict__ wqb,
    const __hip_bfloat16* __restrict__ wpb,
    float* __restrict__ out)
{
    __shared__ __align__(16) unsigned char smem[SMEM_BYTES];
    __hip_bfloat16 (* const xw)[XS]  = reinterpret_cast<__hip_bfloat16(*)[XS]>(smem);
    float          (* const stg)[STS] = reinterpret_cast<float(*)[STS]>(smem);
    __hip_bfloat16* const vTp = reinterpret_cast<__hip_bfloat16*>(smem + OFF_VT);

    const int tid  = threadIdx.x;
    const int lane = tid & 63;
    const int wv   = tid >> 6;      // 0..11
    const int col  = lane & 15;
    const int grp  = lane >> 4;     // 0..3

    // XCD-aware swizzle (1936 % 8 == 0 -> bijective)
    const int wid0 = blockIdx.x;
    const int wid  = (wid0 & 7) * (NWIN / 8) + (wid0 >> 3);
    const int b    = wid / (NHW * NHW);
    const int r0   = wid % (NHW * NHW);
    const int wh   = r0 / NHW;
    const int ww   = r0 % NHW;

    // ---- stage x window (reflect pad) into LDS bf16 [t][c] ----
    for (int u = tid; u < 24 * NTOK; u += 768) {   // u = c8*144 + t
        int c8 = u / NTOK;
        int t  = u - c8 * NTOK;
        int ty = t / WSZ, tx = t - ty * WSZ;
        int h = wh * WSZ + ty; if (h >= RES) h = 2 * RES - 2 - h;
        int w = ww * WSZ + tx; if (w >= RES) w = 2 * RES - 2 - w;
        const float* px = x + ((size_t)(b * 192 + c8 * 8) * RES + h) * RES + w;
        u32x4 uv;
        #pragma unroll
        for (int j = 0; j < 4; ++j)
            uv[j] = pk2(px[(size_t)(2 * j) * RES * RES], px[(size_t)(2 * j + 1) * RES * RES]);
        *(u32x4*)&xw[t][c8 * 8] = uv;
    }
    __syncthreads();

    f32x4 pacc[9];   // proj accumulators; wave owns oc-tile wv
    #pragma unroll
    for (int m = 0; m < 9; ++m) pacc[m] = (f32x4){0.f, 0.f, 0.f, 0.f};

    // qkv wave role: (mh, n6); n6 -> (kind, h2q); wave covers both dh halves
    const int mh   = wv & 1;
    const int n6   = wv >> 1;       // 0..5
    const int kind = n6 >> 1;       // 0=q 1=k 2=v
    const int h2q  = n6 & 1;
    const int mt0  = mh ? 4 : 0;
    const int nmt  = mh ? 5 : 4;    // mh=1 also owns mt8

    auto do_proj = [&](int hpp) {
        #pragma unroll
        for (int h2 = 0; h2 < 2; ++h2) {
            const int hh = hpp * 2 + h2;
            const bf16x8 Bf = WB ? ld8(wpb + (size_t)(wv * 16 + col) * 192 + hh * 32 + grp * 8)
                                 : wfrag(w_proj + (size_t)(wv * 16 + col) * 192 + hh * 32 + grp * 8);
            const __hip_bfloat16 (* const aoPl)[QS] =
                reinterpret_cast<const __hip_bfloat16(*)[QS]>(smem + OFF_AO + h2 * 11520);
            #pragma unroll
            for (int mt = 0; mt < 9; ++mt) {
                const bf16x8 Af = ld8(&aoPl[mt * 16 + col][grp * 8]);
                pacc[mt] = __builtin_amdgcn_mfma_f32_16x16x32_bf16(Af, Bf, pacc[mt], 0, 0, 0);
            }
        }
    };

    for (int hp = 0; hp < 3; ++hp) {
        // ---- merged phase: qkv(hp) + proj(hp-1) ----
        {
            const int hh    = hp * 2 + h2q;
            const int rbase = kind * 192 + hh * 32;
            f32x4 acc[2][5];
            #pragma unroll
            for (int d = 0; d < 2; ++d)
                #pragma unroll
                for (int m = 0; m < 5; ++m) acc[d][m] = (f32x4){0.f, 0.f, 0.f, 0.f};
            #pragma unroll
            for (int k0 = 0; k0 < 6; ++k0) {
                const bf16x8 B0 = WB ? ld8(wqb + (size_t)(rbase + col) * 192 + k0 * 32 + grp * 8)
                                     : wfrag(w_qkv + (size_t)(rbase + col) * 192 + k0 * 32 + grp * 8);
                const bf16x8 B1 = WB ? ld8(wqb + (size_t)(rbase + 16 + col) * 192 + k0 * 32 + grp * 8)
                                     : wfrag(w_qkv + (size_t)(rbase + 16 + col) * 192 + k0 * 32 + grp * 8);
                #pragma unroll
                for (int m = 0; m < 5; ++m) {
                    if (m < nmt) {
                        const bf16x8 Af = ld8(&xw[(mt0 + m) * 16 + col][k0 * 32 + grp * 8]);
                        acc[0][m] = __builtin_amdgcn_mfma_f32_16x16x32_bf16(Af, B0, acc[0][m], 0, 0, 0);
                        acc[1][m] = __builtin_amdgcn_mfma_f32_16x16x32_bf16(Af, B1, acc[1][m], 0, 0, 0);
                    }
                }
            }
            const float qs = (kind == 0) ? SCALE : 1.f;
            if (kind < 2) {
                __hip_bfloat16 (* const pl)[QS] = reinterpret_cast<__hip_bfloat16(*)[QS]>(
                    smem + (kind == 0 ? OFF_Q : OFF_K) + h2q * 11520);
                #pragma unroll
                for (int m = 0; m < 5; ++m) if (m < nmt) {
                    #pragma unroll
                    for (int r = 0; r < 4; ++r) {
                        const int trow = (mt0 + m) * 16 + grp * 4 + r;
                        pl[trow][col]      = __float2bfloat16(acc[0][m][r] * qs);
                        pl[trow][16 + col] = __float2bfloat16(acc[1][m][r] * qs);
                    }
                }
            } else {
                #pragma unroll
                for (int m = 0; m < 5; ++m) if (m < nmt) {
                    #pragma unroll
                    for (int r = 0; r < 4; ++r) {
                        const int t  = (mt0 + m) * 16 + grp * 4 + r;
                        const int ti = t / WSZ, tj = t - ti * WSZ;
                        const int cs   = (ti % 3) * 3 + (tj % 3);
                        const int ctok = (ti / 3) * 4 + (tj / 3);
                        vTp[(size_t)(h2q * 32 + col) * VTS + cs * 16 + ctok]      = __float2bfloat16(acc[0][m][r]);
                        vTp[(size_t)(h2q * 32 + 16 + col) * VTS + cs * 16 + ctok] = __float2bfloat16(acc[1][m][r]);
                    }
                }
            }
            if (hp > 0) do_proj(hp - 1);
        }
        __syncthreads();

        // ---- coset attention: 18 tasks (h2, coset) over 12 waves; writes ao ----
        for (int u = wv; u < 18; u += 12) {
            const int h2 = u / 9;
            const int cs = u % 9;
            __hip_bfloat16 (* const qPl)[QS] = reinterpret_cast<__hip_bfloat16(*)[QS]>(smem + OFF_Q + h2 * 11520);
            __hip_bfloat16 (* const kPl)[QS] = reinterpret_cast<__hip_bfloat16(*)[QS]>(smem + OFF_K + h2 * 11520);
            __hip_bfloat16 (* const aoPl)[QS] = reinterpret_cast<__hip_bfloat16(*)[QS]>(smem + OFF_AO + h2 * 11520);
            const int ci = cs / 3, cj = cs % 3;
            const int tcol = (ci + 3 * (col >> 2)) * WSZ + cj + 3 * (col & 3);
            const bf16x8 Kf = ld8(&kPl[tcol][grp * 8]);
            const bf16x8 Qf = ld8(&qPl[tcol][grp * 8]);
            f32x4 S = {0.f, 0.f, 0.f, 0.f};
            S = __builtin_amdgcn_mfma_f32_16x16x32_bf16(Kf, Qf, S, 0, 0, 0);
            // lane holds S^T: key m = grp*4+r, query n = col
            float e[4]; float mx = -1e30f;
            #pragma unroll
            for (int r = 0; r < 4; ++r) {
                float s = (grp * 4 + r == col) ? -1e30f : S[r];
                e[r] = s;
                mx = fmaxf(mx, s);
            }
            mx = fmaxf(mx, __shfl_xor(mx, 16));
            mx = fmaxf(mx, __shfl_xor(mx, 32));
            float sum = 0.f;
            #pragma unroll
            for (int r = 0; r < 4; ++r) { e[r] = __expf(e[r] - mx); sum += e[r]; }
            sum += __shfl_xor(sum, 16);
            sum += __shfl_xor(sum, 32);
            const float inv = 1.f / sum;
            const unsigned w0 = pk2(e[0] * inv, e[1] * inv);
            const unsigned w1 = pk2(e[2] * inv, e[3] * inv);
            // P -> B-fragment: lane(col,grp<2) holds P[q=col][k=grp*8+j]
            u32x4 pa = {0u, 0u, 0u, 0u};
            {
                const int sA = (col + 32 * grp) * 4;
                int q0 = __builtin_amdgcn_ds_bpermute(sA,      (int)w0);
                int q1 = __builtin_amdgcn_ds_bpermute(sA,      (int)w1);
                int q2 = __builtin_amdgcn_ds_bpermute(sA + 64, (int)w0);
                int q3 = __builtin_amdgcn_ds_bpermute(sA + 64, (int)w1);
                if (grp < 2) pa = (u32x4){(unsigned)q0, (unsigned)q1, (unsigned)q2, (unsigned)q3};
            }
            const bf16x8 PB = __builtin_bit_cast(bf16x8, pa);
            // swapped PV: O^T = mfma(A=V^T, B=P)
            #pragma unroll
            for (int d0 = 0; d0 < 2; ++d0) {
                const bf16x8 VA = ld8(&vTp[(size_t)(h2 * 32 + d0 * 16 + col) * VTS + cs * 16 + (grp & 1) * 8]);
                f32x4 O = {0.f, 0.f, 0.f, 0.f};
                O = __builtin_amdgcn_mfma_f32_16x16x32_bf16(VA, PB, O, 0, 0, 0);
                #pragma unroll
                for (int r = 0; r < 4; ++r)
                    aoPl[tcol][d0 * 16 + grp * 4 + r] = __float2bfloat16(O[r]);
            }
        }
        __syncthreads();
    }

    // ---- final proj for last head pair ----
    do_proj(2);
    __syncthreads();

    // ---- epilogue: stage all 192 oc as f32 [oc][t] (overlays dead x/q/k/vT) ----
    {
        const int ocl = wv * 16 + col;
        #pragma unroll
        for (int mt = 0; mt < 9; ++mt) {
            float4 v4 = make_float4(pacc[mt][0], pacc[mt][1], pacc[mt][2], pacc[mt][3]);
            *(float4*)&stg[ocl][mt * 16 + grp * 4] = v4;
        }
    }
    __syncthreads();
    #pragma unroll
    for (int it = 0; it < 9; ++it) {
        int v = tid + it * 768;          // 0..6911 = (oc, ty, seg)
        int seg = v % 3;
        int rest = v / 3;
        int ty = rest % 12;
        int oc = rest / 12;
        int h  = wh * WSZ + ty;
        int w0 = ww * WSZ + seg * 4;
        if (h < RES && w0 < RES) {
            float4 val = *(const float4*)&stg[oc][ty * 12 + seg * 4];
            *(float4*)&out[((size_t)(b * 192 + oc) * RES + h) * RES + w0] = val;
        }
    }
}

extern "C" void kernel_launch(void* const* d_in, const int* in_sizes, int n_in,
                              void* d_out, int out_size, void* d_ws, size_t ws_size,
                              hipStream_t stream) {
    const float* x      = (const float*)d_in[0];
    const float* w_qkv  = (const float*)d_in[1];
    const float* w_proj = (const float*)d_in[2];
    float* out = (float*)d_out;
    if (ws_size >= (size_t)WS_NEED) {
        __hip_bfloat16* wqb = (__hip_bfloat16*)d_ws;
        __hip_bfloat16* wpb = wqb + WQ_ELEMS;
        conv_w<<<dim3((WQ_ELEMS + 255) / 256), dim3(256), 0, stream>>>(w_qkv, w_proj, wqb);
        wsa_kernel<true><<<dim3(NWIN), dim3(768), 0, stream>>>(x, w_qkv, w_proj, wqb, wpb, out);
    } else {
        wsa_kernel<false><<<dim3(NWIN), dim3(768), 0, stream>>>(x, w_qkv, w_proj, nullptr, nullptr, out);
    }
}

// Round 14
// 292.995 us; speedup vs baseline: 1.2017x; 1.0033x over previous
//
#include <hip/hip_runtime.h>
#include <hip/hip_bf16.h>

typedef __bf16 bf16x8 __attribute__((ext_vector_type(8)));
typedef float f32x4 __attribute__((ext_vector_type(4)));
typedef unsigned int u32x4 __attribute__((ext_vector_type(4)));

#define WSZ 12
#define NTOK 144
#define RES 256
#define NHW 22
#define NWIN (4*NHW*NHW)
#define SCALE 0.17677669529663687f
#define XS 200    // x row stride (bf16): 400 B, 16B-aligned, 2-way banks
#define QS 40     // q/k/ao plane row stride (bf16): 80 B, 16B-aligned
#define VTS 152   // vT row stride (bf16): 304 B, 16B-aligned
#define STS 148   // stg row stride (f32): 592 B, 16B-aligned

#define WQ_ELEMS (576*192)
#define WP_ELEMS (192*192)
#define WS_NEED ((WQ_ELEMS + WP_ELEMS) * 2)

// LDS byte offsets
#define OFF_Q  57600                       // q planes: 2 x [144][40] bf16
#define OFF_K  (OFF_Q + 2*11520)           // k planes: 2 x [144][40] bf16  (80640)
#define OFF_VT (OFF_K + 2*11520)           // vT: [2][32][152] bf16         (103680)
#define OFF_AO (OFF_VT + 2*32*VTS*2)       // ao planes: 2 x [144][40] bf16 (123136)
#define SMEM_BYTES (OFF_AO + 2*NTOK*QS*2)  // 146176 B
// stg overlays [0 .. 192*STS*4 = 113664) — xw/q/k/vT region, disjoint from ao

static __device__ __forceinline__ unsigned f2u(float f) {
    return (unsigned)__builtin_bit_cast(unsigned short, __float2bfloat16(f));
}
static __device__ __forceinline__ unsigned pk2(float a, float b) {
    return f2u(a) | (f2u(b) << 16);
}
static __device__ __forceinline__ bf16x8 ld8(const void* p) {
    return *(const bf16x8*)p;
}
static __device__ __forceinline__ bf16x8 wfrag(const float* p) {
    const float4* p4 = (const float4*)p;
    float4 lo = p4[0], hi = p4[1];
    u32x4 u = { pk2(lo.x, lo.y), pk2(lo.z, lo.w), pk2(hi.x, hi.y), pk2(hi.z, hi.w) };
    return __builtin_bit_cast(bf16x8, u);
}

__global__ __launch_bounds__(256) void conv_w(const float* __restrict__ wq,
                                              const float* __restrict__ wp,
                                              __hip_bfloat16* __restrict__ dst) {
    int i = blockIdx.x * 256 + threadIdx.x;
    if (i < WQ_ELEMS) dst[i] = __float2bfloat16(wq[i]);
    if (i < WP_ELEMS) dst[WQ_ELEMS + i] = __float2bfloat16(wp[i]);
}

template<bool WB>
__global__ __launch_bounds__(768, 2) void wsa_kernel(
    const float* __restrict__ x,
    const float* __restrict__ w_qkv,
    const float* __restrict__ w_proj,
    const __hip_bfloat16* __restrict__ wqb,
    const __hip_bfloat16* __restrict__ wpb,
    float* __restrict__ out)
{
    __shared__ __align__(16) unsigned char smem[SMEM_BYTES];
    __hip_bfloat16 (* const xw)[XS]  = reinterpret_cast<__hip_bfloat16(*)[XS]>(smem);
    float          (* const stg)[STS] = reinterpret_cast<float(*)[STS]>(smem);
    __hip_bfloat16* const vTp = reinterpret_cast<__hip_bfloat16*>(smem + OFF_VT);

    const int tid  = threadIdx.x;
    const int lane = tid & 63;
    const int wv   = tid >> 6;      // 0..11
    const int col  = lane & 15;
    const int grp  = lane >> 4;     // 0..3

    // XCD-aware swizzle (1936 % 8 == 0 -> bijective)
    const int wid0 = blockIdx.x;
    const int wid  = (wid0 & 7) * (NWIN / 8) + (wid0 >> 3);
    const int b    = wid / (NHW * NHW);
    const int r0   = wid % (NHW * NHW);
    const int wh   = r0 / NHW;
    const int ww   = r0 % NHW;

    // ---- stage x window (reflect pad) into LDS bf16 [t][c] ----
    for (int u = tid; u < 24 * NTOK; u += 768) {   // u = c8*144 + t
        int c8 = u / NTOK;
        int t  = u - c8 * NTOK;
        int ty = t / WSZ, tx = t - ty * WSZ;
        int h = wh * WSZ + ty; if (h >= RES) h = 2 * RES - 2 - h;
        int w = ww * WSZ + tx; if (w >= RES) w = 2 * RES - 2 - w;
        const float* px = x + ((size_t)(b * 192 + c8 * 8) * RES + h) * RES + w;
        u32x4 uv;
        #pragma unroll
        for (int j = 0; j < 4; ++j)
            uv[j] = pk2(px[(size_t)(2 * j) * RES * RES], px[(size_t)(2 * j + 1) * RES * RES]);
        *(u32x4*)&xw[t][c8 * 8] = uv;
    }
    __syncthreads();

    f32x4 pacc[9];   // proj accumulators; wave owns oc-tile wv
    #pragma unroll
    for (int m = 0; m < 9; ++m) pacc[m] = (f32x4){0.f, 0.f, 0.f, 0.f};

    // qkv wave role: (mh, n6); n6 -> (kind, h2q); wave covers both dh halves
    const int mh   = wv & 1;
    const int n6   = wv >> 1;       // 0..5
    const int kind = n6 >> 1;       // 0=q 1=k 2=v
    const int h2q  = n6 & 1;
    const int mt0  = mh ? 4 : 0;
    const int nmt  = mh ? 5 : 4;    // mh=1 also owns mt8

    auto do_proj = [&](int hpp) {
        #pragma unroll
        for (int h2 = 0; h2 < 2; ++h2) {
            const int hh = hpp * 2 + h2;
            const bf16x8 Bf = WB ? ld8(wpb + (size_t)(wv * 16 + col) * 192 + hh * 32 + grp * 8)
                                 : wfrag(w_proj + (size_t)(wv * 16 + col) * 192 + hh * 32 + grp * 8);
            const __hip_bfloat16 (* const aoPl)[QS] =
                reinterpret_cast<const __hip_bfloat16(*)[QS]>(smem + OFF_AO + h2 * 11520);
            #pragma unroll
            for (int mt = 0; mt < 9; ++mt) {
                const bf16x8 Af = ld8(&aoPl[mt * 16 + col][grp * 8]);
                pacc[mt] = __builtin_amdgcn_mfma_f32_16x16x32_bf16(Af, Bf, pacc[mt], 0, 0, 0);
            }
        }
    };

    for (int hp = 0; hp < 3; ++hp) {
        // ---- merged phase: qkv(hp) + proj(hp-1) ----
        {
            const int hh    = hp * 2 + h2q;
            const int rbase = kind * 192 + hh * 32;
            f32x4 acc[2][5];
            #pragma unroll
            for (int d = 0; d < 2; ++d)
                #pragma unroll
                for (int m = 0; m < 5; ++m) acc[d][m] = (f32x4){0.f, 0.f, 0.f, 0.f};
            #pragma unroll
            for (int k0 = 0; k0 < 6; ++k0) {
                const bf16x8 B0 = WB ? ld8(wqb + (size_t)(rbase + col) * 192 + k0 * 32 + grp * 8)
                                     : wfrag(w_qkv + (size_t)(rbase + col) * 192 + k0 * 32 + grp * 8);
                const bf16x8 B1 = WB ? ld8(wqb + (size_t)(rbase + 16 + col) * 192 + k0 * 32 + grp * 8)
                                     : wfrag(w_qkv + (size_t)(rbase + 16 + col) * 192 + k0 * 32 + grp * 8);
                #pragma unroll
                for (int m = 0; m < 5; ++m) {
                    if (m < nmt) {
                        const bf16x8 Af = ld8(&xw[(mt0 + m) * 16 + col][k0 * 32 + grp * 8]);
                        acc[0][m] = __builtin_amdgcn_mfma_f32_16x16x32_bf16(Af, B0, acc[0][m], 0, 0, 0);
                        acc[1][m] = __builtin_amdgcn_mfma_f32_16x16x32_bf16(Af, B1, acc[1][m], 0, 0, 0);
                    }
                }
            }
            const float qs = (kind == 0) ? SCALE : 1.f;
            if (kind < 2) {
                __hip_bfloat16 (* const pl)[QS] = reinterpret_cast<__hip_bfloat16(*)[QS]>(
                    smem + (kind == 0 ? OFF_Q : OFF_K) + h2q * 11520);
                #pragma unroll
                for (int m = 0; m < 5; ++m) if (m < nmt) {
                    #pragma unroll
                    for (int r = 0; r < 4; ++r) {
                        const int trow = (mt0 + m) * 16 + grp * 4 + r;
                        pl[trow][col]      = __float2bfloat16(acc[0][m][r] * qs);
                        pl[trow][16 + col] = __float2bfloat16(acc[1][m][r] * qs);
                    }
                }
            } else {
                #pragma unroll
                for (int m = 0; m < 5; ++m) if (m < nmt) {
                    #pragma unroll
                    for (int r = 0; r < 4; ++r) {
                        const int t  = (mt0 + m) * 16 + grp * 4 + r;
                        const int ti = t / WSZ, tj = t - ti * WSZ;
                        const int cs   = (ti % 3) * 3 + (tj % 3);
                        const int ctok = (ti / 3) * 4 + (tj / 3);
                        vTp[(size_t)(h2q * 32 + col) * VTS + cs * 16 + ctok]      = __float2bfloat16(acc[0][m][r]);
                        vTp[(size_t)(h2q * 32 + 16 + col) * VTS + cs * 16 + ctok] = __float2bfloat16(acc[1][m][r]);
                    }
                }
            }
            if (hp > 0) do_proj(hp - 1);
        }
        __syncthreads();

        // ---- coset attention: 18 tasks (h2, coset) over 12 waves; writes ao ----
        for (int u = wv; u < 18; u += 12) {
            const int h2 = u / 9;
            const int cs = u % 9;
            __hip_bfloat16 (* const qPl)[QS] = reinterpret_cast<__hip_bfloat16(*)[QS]>(smem + OFF_Q + h2 * 11520);
            __hip_bfloat16 (* const kPl)[QS] = reinterpret_cast<__hip_bfloat16(*)[QS]>(smem + OFF_K + h2 * 11520);
            __hip_bfloat16 (* const aoPl)[QS] = reinterpret_cast<__hip_bfloat16(*)[QS]>(smem + OFF_AO + h2 * 11520);
            const int ci = cs / 3, cj = cs % 3;
            const int tcol = (ci + 3 * (col >> 2)) * WSZ + cj + 3 * (col & 3);
            const bf16x8 Kf = ld8(&kPl[tcol][grp * 8]);
            const bf16x8 Qf = ld8(&qPl[tcol][grp * 8]);
            f32x4 S = {0.f, 0.f, 0.f, 0.f};
            S = __builtin_amdgcn_mfma_f32_16x16x32_bf16(Kf, Qf, S, 0, 0, 0);
            // lane holds S^T: key m = grp*4+r, query n = col
            float e[4]; float mx = -1e30f;
            #pragma unroll
            for (int r = 0; r < 4; ++r) {
                float s = (grp * 4 + r == col) ? -1e30f : S[r];
                e[r] = s;
                mx = fmaxf(mx, s);
            }
            mx = fmaxf(mx, __shfl_xor(mx, 16));
            mx = fmaxf(mx, __shfl_xor(mx, 32));
            float sum = 0.f;
            #pragma unroll
            for (int r = 0; r < 4; ++r) { e[r] = __expf(e[r] - mx); sum += e[r]; }
            sum += __shfl_xor(sum, 16);
            sum += __shfl_xor(sum, 32);
            const float inv = 1.f / sum;
            const unsigned w0 = pk2(e[0] * inv, e[1] * inv);
            const unsigned w1 = pk2(e[2] * inv, e[3] * inv);
            // P -> B-fragment: lane(col,grp<2) holds P[q=col][k=grp*8+j]
            u32x4 pa = {0u, 0u, 0u, 0u};
            {
                const int sA = (col + 32 * grp) * 4;
                int q0 = __builtin_amdgcn_ds_bpermute(sA,      (int)w0);
                int q1 = __builtin_amdgcn_ds_bpermute(sA,      (int)w1);
                int q2 = __builtin_amdgcn_ds_bpermute(sA + 64, (int)w0);
                int q3 = __builtin_amdgcn_ds_bpermute(sA + 64, (int)w1);
                if (grp < 2) pa = (u32x4){(unsigned)q0, (unsigned)q1, (unsigned)q2, (unsigned)q3};
            }
            const bf16x8 PB = __builtin_bit_cast(bf16x8, pa);
            // swapped PV: O^T = mfma(A=V^T, B=P)
            #pragma unroll
            for (int d0 = 0; d0 < 2; ++d0) {
                const bf16x8 VA = ld8(&vTp[(size_t)(h2 * 32 + d0 * 16 + col) * VTS + cs * 16 + (grp & 1) * 8]);
                f32x4 O = {0.f, 0.f, 0.f, 0.f};
                O = __builtin_amdgcn_mfma_f32_16x16x32_bf16(VA, PB, O, 0, 0, 0);
                #pragma unroll
                for (int r = 0; r < 4; ++r)
                    aoPl[tcol][d0 * 16 + grp * 4 + r] = __float2bfloat16(O[r]);
            }
        }
        __syncthreads();
    }

    // ---- final proj for last head pair ----
    do_proj(2);
    __syncthreads();

    // ---- epilogue: stage all 192 oc as f32 [oc][t] (overlays dead x/q/k/vT) ----
    {
        const int ocl = wv * 16 + col;
        #pragma unroll
        for (int mt = 0; mt < 9; ++mt) {
            float4 v4 = make_float4(pacc[mt][0], pacc[mt][1], pacc[mt][2], pacc[mt][3]);
            *(float4*)&stg[ocl][mt * 16 + grp * 4] = v4;
        }
    }
    __syncthreads();
    #pragma unroll
    for (int it = 0; it < 9; ++it) {
        int v = tid + it * 768;          // 0..6911 = (oc, ty, seg)
        int seg = v % 3;
        int rest = v / 3;
        int ty = rest % 12;
        int oc = rest / 12;
        int h  = wh * WSZ + ty;
        int w0 = ww * WSZ + seg * 4;
        if (h < RES && w0 < RES) {
            float4 val = *(const float4*)&stg[oc][ty * 12 + seg * 4];
            *(float4*)&out[((size_t)(b * 192 + oc) * RES + h) * RES + w0] = val;
        }
    }
}

extern "C" void kernel_launch(void* const* d_in, const int* in_sizes, int n_in,
                              void* d_out, int out_size, void* d_ws, size_t ws_size,
                              hipStream_t stream) {
    const float* x      = (const float*)d_in[0];
    const float* w_qkv  = (const float*)d_in[1];
    const float* w_proj = (const float*)d_in[2];
    float* out = (float*)d_out;
    if (ws_size >= (size_t)WS_NEED) {
        __hip_bfloat16* wqb = (__hip_bfloat16*)d_ws;
        __hip_bfloat16* wpb = wqb + WQ_ELEMS;
        conv_w<<<dim3((WQ_ELEMS + 255) / 256), dim3(256), 0, stream>>>(w_qkv, w_proj, wqb);
        wsa_kernel<true><<<dim3(NWIN), dim3(768), 0, stream>>>(x, w_qkv, w_proj, wqb, wpb, out);
    } else {
        wsa_kernel<false><<<dim3(NWIN), dim3(768), 0, stream>>>(x, w_qkv, w_proj, nullptr, nullptr, out);
    }
}